// Round 5
// baseline (1204.189 us; speedup 1.0000x reference)
//
#include <hip/hip_runtime.h>
#include <cstdint>
#include <cstddef>

// WaveNet forward, fp16-MFMA v3 (t-major layouts, 32x32x16 MFMA, 2 WG/CU).
//   B=4, T=8192, NC=256, NMEL=640, NL=8, K=3 (dilated 2^i)
// Layouts: audio ping/pong (B, TROWS=8448, 256) fp16 t-major, guard rows +-128;
//          spect_t (B, T, 640) fp16 t-major; outbuf (B, T, 256) fp16 t-major.
// Per layer kernel: WG = 512 thr = 8 waves, tile 512 rows x 64 cols.
//   Wave w: rows {32w..32w+31} u {256+32w..+31} (gate pairs in-register).
//   K = 1408 = 22 blocks of 64. B-tile staged via global_load_lds (16B/thread)
//   with source-side inverse XOR swizzle, linear LDS dest (G21).
//   LDS rows 128 B, pslot = slot ^ (col&7) ^ ((col>>3)&7)  -> uniform banks.
// rs GEMM (K=256) fused via acts in LDS (same swizzle family, 512-B rows).

constexpr int T_LEN = 8192;
constexpr int NB    = 4;
constexpr int NC    = 256;
constexpr int NMEL  = 640;
constexpr int NL    = 8;
constexpr int KTOT  = NMEL + 3 * NC;      // 1408 = 22 * 64
constexpr int GUARD = 128;
constexpr int TROWS = T_LEN + 2 * GUARD;  // 8448
constexpr int NCOL  = 64;

typedef _Float16 half8 __attribute__((ext_vector_type(8)));
typedef _Float16 half4 __attribute__((ext_vector_type(4)));
typedef float f32x16 __attribute__((ext_vector_type(16)));

__device__ __forceinline__ half8 ldg8(const _Float16* p, unsigned boff) {
    return *(const half8*)((const unsigned char*)p + boff);
}

__device__ __forceinline__ void gld_lds16(const void* g, void* l) {
    __builtin_amdgcn_global_load_lds(
        (const __attribute__((address_space(1))) unsigned int*)g,
        (__attribute__((address_space(3))) unsigned int*)l, 16, 0, 0);
}

#define MFMA32(A, B, C) __builtin_amdgcn_mfma_f32_32x32x16_f16((A), (B), (C), 0, 0, 0)

// ------------------------------------------------------------- layer kernel
__global__ __launch_bounds__(512, 4) void wavenet_layer(
    const _Float16* __restrict__ aud_rd_g,   // (B,TROWS,256) ping
    _Float16* __restrict__ aud_wr_g,         // pong
    const _Float16* __restrict__ spect_t,    // (B,T,640)
    const _Float16* __restrict__ W1l,        // (512,1408)
    const float* __restrict__ bias1_l,       // (512)
    const _Float16* __restrict__ RSl,        // (512,256)
    const float* __restrict__ rs_b_l,        // (512)
    _Float16* __restrict__ outbuf,           // (B,T,256)
    int dil, int last)
{
    // Bs: buf*16384 + col*128 + pslot*16   (2 bufs x 64 col x 64 k halfs)
    // acts (union, after K-loop): col*512 + pslot*16  (64 col x 256 ch halfs)
    __shared__ __align__(16) unsigned char smem[32768];

    const int tid = threadIdx.x;
    const int c31 = tid & 31;
    const int h2  = (tid >> 5) & 1;
    const int w   = tid >> 6;

    // bijective XCD swizzle of 512 tiles (t-tile fast, batch slow)
    const int bid = blockIdx.x;
    const int swz = (bid & 7) * 64 + (bid >> 3);
    const int n0  = (swz & 127) * NCOL;
    const int b   = swz >> 7;

    const _Float16* aud_rd = aud_rd_g + (size_t)b * TROWS * NC;
    _Float16*       aud_wr = aud_wr_g + (size_t)b * TROWS * NC;
    const _Float16* sp_b   = spect_t + (size_t)b * T_LEN * NMEL;
    _Float16*       out_b  = outbuf + (size_t)b * T_LEN * NC;

    // ---- staging map: thread -> (col sc, phys slot ps); logical slot via XOR
    const int sc   = tid >> 3;
    const int ps   = tid & 7;
    const int slog = ps ^ (sc & 7) ^ ((sc >> 3) & 7);
    unsigned voffSb = (unsigned)(((n0 + sc) * NMEL + 8 * slog) * 2);
    unsigned voffAb = (unsigned)(((GUARD + n0 + sc - dil) * NC + 8 * slog) * 2);
    const unsigned dilstep = (unsigned)(dil * 512 - 384);
    unsigned char* ldst = smem + tid * 16;        // linear dest (per-lane x16B)

    // ---- MFMA read constants
    const int xc0 = (c31 & 7) ^ ((c31 >> 3) & 7);
    const int hx0 = ((h2 ^ xc0) << 4);
    const int hx1 = ((h2 ^ xc0 ^ 4) << 4);
    const int rb0 = c31 * 128;
    const int rb1 = (32 + c31) * 128;

    const int mrow0 = 32 * w;
    const int mrow1 = 256 + 32 * w;
    unsigned voffW0 = (unsigned)(((mrow0 + c31) * KTOT + 8 * h2) * 2);
    unsigned voffW1 = (unsigned)(((mrow1 + c31) * KTOT + 8 * h2) * 2);

    const f32x16 fz = {0.f,0.f,0.f,0.f,0.f,0.f,0.f,0.f,0.f,0.f,0.f,0.f,0.f,0.f,0.f,0.f};
    f32x16 acc00 = fz, acc01 = fz, acc10 = fz, acc11 = fz;

#define GLD(SS, BUF)                                                          \
    {                                                                         \
        if ((SS) <= 9) {                                                      \
            gld_lds16((const unsigned char*)sp_b + voffSb,                    \
                      smem + (BUF) * 16384 + tid * 16);                       \
            voffSb += 128;                                                    \
        } else if ((SS) <= 21) {                                              \
            gld_lds16((const unsigned char*)aud_rd + voffAb,                  \
                      smem + (BUF) * 16384 + tid * 16);                       \
            voffAb += ((SS) == 13 || (SS) == 17) ? dilstep : 128u;            \
        }                                                                     \
    }

#define HSTEP(CUR, SS)                                                        \
    {                                                                         \
        GLD(SS, (CUR) ^ 1)                                                    \
        __builtin_amdgcn_s_setprio(1);                                        \
        _Pragma("unroll") for (int ks = 0; ks < 4; ++ks) {                    \
            half8 a0 = ldg8(W1l, voffW0 + 32 * ks);                           \
            half8 a1 = ldg8(W1l, voffW1 + 32 * ks);                           \
            half8 b0 = *(const half8*)(smem + (CUR) * 16384 + rb0 +           \
                                       ((ks << 5) ^ hx0));                    \
            half8 b1 = *(const half8*)(smem + (CUR) * 16384 + rb1 +           \
                                       ((ks << 5) ^ hx1));                    \
            acc00 = MFMA32(a0, b0, acc00);                                    \
            acc01 = MFMA32(a0, b1, acc01);                                    \
            acc10 = MFMA32(a1, b0, acc10);                                    \
            acc11 = MFMA32(a1, b1, acc11);                                    \
        }                                                                     \
        __builtin_amdgcn_s_setprio(0);                                        \
        voffW0 += 128; voffW1 += 128;                                         \
        __syncthreads();                                                      \
    }

    // prologue: block 0 -> buf0
    GLD(0, 0)
    __syncthreads();

    #pragma unroll 1
    for (int it = 0; it < 11; ++it) {
        HSTEP(0, it * 2 + 1)
        HSTEP(1, it * 2 + 2)
    }
#undef HSTEP
#undef GLD

    // ---- gate: acts[c] = tanh(pre[c]) * sigmoid(pre[c+256]) -> LDS (swizzled)
    #pragma unroll
    for (int nn = 0; nn < 2; ++nn) {
        const f32x16& p0v = nn ? acc01 : acc00;
        const f32x16& p1v = nn ? acc11 : acc10;
        const int colb = (32 * nn + c31) * 512;
        const int xcn  = nn ? (xc0 ^ 4) : xc0;
        #pragma unroll
        for (int g = 0; g < 4; ++g) {
            half4 hv;
            #pragma unroll
            for (int r = 0; r < 4; ++r) {
                int ch   = 32 * w + 8 * g + 4 * h2 + r;
                float p0 = p0v[4 * g + r] + bias1_l[ch];
                float p1 = p1v[4 * g + r] + bias1_l[256 + ch];
                float th = 1.f - 2.f / (1.f + __expf(2.f * p0));
                float sg = 1.f / (1.f + __expf(-p1));
                hv[r] = (_Float16)(th * sg);
            }
            int slot = 4 * w + g;
            *(half4*)(smem + colb + ((slot ^ xcn) << 4) + 8 * h2) = hv;
        }
    }
    __syncthreads();

    // ---- rs GEMM: K=256 from acts
    f32x16 r00 = fz, r01 = fz, r10 = fz, r11 = fz;
    unsigned voffR0 = (unsigned)(((mrow0 + c31) * NC + 8 * h2) * 2);
    unsigned voffR1 = (unsigned)(((mrow1 + c31) * NC + 8 * h2) * 2);
    #pragma unroll
    for (int ksl = 0; ksl < 16; ++ksl) {
        half8 a0 = ldg8(RSl, voffR0 + 32 * ksl);
        half8 a1 = ldg8(RSl, voffR1 + 32 * ksl);
        half8 b0 = *(const half8*)(smem + c31 * 512 + ((ksl << 5) ^ hx0));
        half8 b1 = *(const half8*)(smem + (32 + c31) * 512 + ((ksl << 5) ^ hx1));
        r00 = MFMA32(a0, b0, r00);
        r01 = MFMA32(a0, b1, r01);
        r10 = MFMA32(a1, b0, r10);
        r11 = MFMA32(a1, b1, r11);
    }

    // ---- epilogue: audio_out = audio_in + rsa[:256]; outbuf += rsa[256:]
    #pragma unroll
    for (int nn = 0; nn < 2; ++nn) {
        const f32x16& v0 = nn ? r01 : r00;
        const f32x16& v1 = nn ? r11 : r10;
        const int t = n0 + 32 * nn + c31;
        #pragma unroll
        for (int g = 0; g < 4; ++g) {
            const int ch0 = 32 * w + 8 * g + 4 * h2;
            if (last) {
                size_t oi = (size_t)t * NC + ch0;
                half4 o = *(const half4*)(out_b + oi);
                half4 nv;
                #pragma unroll
                for (int r = 0; r < 4; ++r)
                    nv[r] = (_Float16)((float)o[r] + v0[4 * g + r] + rs_b_l[ch0 + r]);
                *(half4*)(out_b + oi) = nv;
            } else {
                size_t ai = (size_t)(GUARD + t) * NC + ch0;
                half4 o = *(const half4*)(aud_rd + ai);
                half4 nv;
                #pragma unroll
                for (int r = 0; r < 4; ++r)
                    nv[r] = (_Float16)((float)o[r] + v0[4 * g + r] + rs_b_l[ch0 + r]);
                *(half4*)(aud_wr + ai) = nv;

                size_t oi = (size_t)t * NC + ch0;
                half4 os = *(const half4*)(out_b + oi);
                half4 ns;
                #pragma unroll
                for (int r = 0; r < 4; ++r)
                    ns[r] = (_Float16)((float)os[r] + v1[4 * g + r] +
                                       rs_b_l[256 + ch0 + r]);
                *(half4*)(out_b + oi) = ns;
            }
        }
    }
}

// ------------------------------------------------------------- pack weights
__global__ __launch_bounds__(256) void pack_kernel(
    const float* __restrict__ cond_w, const float* __restrict__ in_w,
    const float* __restrict__ rs_w, const float* __restrict__ in_b,
    const float* __restrict__ cond_b,
    _Float16* __restrict__ W1h, _Float16* __restrict__ RSh,
    float* __restrict__ bias1)
{
    constexpr int SZ_W1 = NL * 512 * KTOT;       // 5,767,168
    constexpr int SZ_RS = NL * 512 * NC;         // 1,048,576
    int idx = blockIdx.x * 256 + threadIdx.x;
    if (idx < SZ_W1) {
        int lyr = idx / (512 * KTOT);
        int r1  = idx - lyr * (512 * KTOT);
        int m   = r1 / KTOT;
        int k   = r1 - m * KTOT;
        float v;
        if (k < NMEL) {
            v = cond_w[(size_t)(lyr * 512 + m) * NMEL + k];
        } else {
            int kin = k - NMEL;
            int kk = kin >> 8, cc = kin & 255;   // tap-major
            v = in_w[((size_t)(lyr * 512 + m) * NC + cc) * 3 + kk];
        }
        W1h[idx] = (_Float16)v;
    } else if (idx < SZ_W1 + SZ_RS) {
        int i2 = idx - SZ_W1;
        RSh[i2] = (_Float16)rs_w[i2];
    } else if (idx < SZ_W1 + SZ_RS + NL * 512) {
        int i3 = idx - SZ_W1 - SZ_RS;
        bias1[i3] = in_b[i3] + cond_b[i3];
    }
}

// ------------------------------------------------- spect fp32 (c,t) -> fp16 (t,c)
__global__ __launch_bounds__(256) void spect_tr_kernel(
    const float* __restrict__ spect, _Float16* __restrict__ spect_t)
{
    int t0 = blockIdx.x * 64;
    int b  = blockIdx.z;
    int tt = threadIdx.x & 63;
    int gg = threadIdx.x >> 6;
    const float* sb = spect + (size_t)b * NMEL * T_LEN + t0 + tt;
    _Float16*    ob = spect_t + (size_t)b * T_LEN * NMEL + (size_t)(t0 + tt) * NMEL;
    #pragma unroll 1
    for (int g = gg; g < 80; g += 4) {
        half8 v;
        #pragma unroll
        for (int j = 0; j < 8; ++j)
            v[j] = (_Float16)sb[(size_t)(8 * g + j) * T_LEN];
        *(half8*)(ob + 8 * g) = v;
    }
}

// ------------------------------------------------------------- guard zero
__global__ __launch_bounds__(256) void guard_zero_kernel(
    _Float16* __restrict__ a0, _Float16* __restrict__ a1)
{
    int idx = blockIdx.x * 256 + threadIdx.x;    // 131072 threads
    int q  = idx & 16383;
    int rg = q >> 6;
    int ck = q & 63;
    int b  = (idx >> 14) & 3;
    _Float16* base = (idx >> 16) ? a1 : a0;
    int row = (rg < 128) ? rg : rg + 8192;       // [0,128) u [8320,8448)
    half4 z = {};
    *(half4*)(base + (size_t)b * TROWS * NC + (size_t)row * NC + ck * 4) = z;
}

// ------------------------------------------------------------- start conv
__global__ __launch_bounds__(256) void start_kernel(
    const float* __restrict__ audio_in,  // (B,4,T)
    const float* __restrict__ start_w,   // (256,4)
    const float* __restrict__ start_b,   // (256)
    _Float16* __restrict__ audio0,       // (B,TROWS,256) t-major
    _Float16* __restrict__ outbuf)       // (B,T,256) -> zero
{
    int idx = blockIdx.x * 256 + threadIdx.x;    // B*T*64 threads
    int c4 = (idx & 63) * 4;
    int t  = (idx >> 6) & (T_LEN - 1);
    int b  = idx >> 19;
    float a[4];
    #pragma unroll
    for (int i = 0; i < 4; ++i)
        a[i] = audio_in[((size_t)b * 4 + i) * T_LEN + t];
    half4 hv;
    #pragma unroll
    for (int r = 0; r < 4; ++r) {
        float acc = start_b[c4 + r];
        #pragma unroll
        for (int i = 0; i < 4; ++i)
            acc += start_w[(c4 + r) * 4 + i] * a[i];
        hv[r] = (_Float16)acc;
    }
    *(half4*)(audio0 + (size_t)b * TROWS * NC + (size_t)(GUARD + t) * NC + c4) = hv;
    half4 z = {};
    *(half4*)(outbuf + (size_t)b * T_LEN * NC + (size_t)t * NC + c4) = z;
}

// ------------------------------------------------------------- end conv
__global__ __launch_bounds__(256) void end_kernel(
    const _Float16* __restrict__ outbuf, // (B,T,256)
    const float* __restrict__ end_w,     // (8,256)
    const float* __restrict__ end_b,     // (8)
    float* __restrict__ out)             // (B,8,T)
{
    int idx = blockIdx.x * 256 + threadIdx.x;    // B*T threads
    int t = idx & (T_LEN - 1);
    int b = idx >> 13;
    const _Float16* ob = outbuf + (size_t)b * T_LEN * NC + (size_t)t * NC;
    float acc[8];
    #pragma unroll
    for (int o = 0; o < 8; ++o) acc[o] = end_b[o];
    #pragma unroll 1
    for (int c8 = 0; c8 < 32; ++c8) {
        half8 x = *(const half8*)(ob + c8 * 8);
        #pragma unroll
        for (int j = 0; j < 8; ++j) {
            float xf = (float)x[j];
            #pragma unroll
            for (int o = 0; o < 8; ++o)
                acc[o] += end_w[o * NC + c8 * 8 + j] * xf;
        }
    }
    #pragma unroll
    for (int o = 0; o < 8; ++o)
        out[((size_t)b * 8 + o) * T_LEN + t] = acc[o];
}

// ------------------------------------------------------------- launcher
extern "C" void kernel_launch(void* const* d_in, const int* in_sizes, int n_in,
                              void* d_out, int out_size, void* d_ws, size_t ws_size,
                              hipStream_t stream)
{
    const float* spect    = (const float*)d_in[0];
    const float* audio_in = (const float*)d_in[1];
    const float* start_w  = (const float*)d_in[2];
    const float* start_b  = (const float*)d_in[3];
    const float* cond_w   = (const float*)d_in[4];
    const float* cond_b   = (const float*)d_in[5];
    const float* in_w     = (const float*)d_in[6];
    const float* in_b     = (const float*)d_in[7];
    const float* rs_w     = (const float*)d_in[8];
    const float* rs_b     = (const float*)d_in[9];
    const float* end_w    = (const float*)d_in[10];
    const float* end_b    = (const float*)d_in[11];
    float* out = (float*)d_out;

    // ws layout (bytes):
    //   W1h 11,534,336 | RSh 2,097,152 | bias1 16,384 | outbuf(f16) 16,777,216
    //   audio0 17,301,504 | audio1 17,301,504 | spect_t 41,943,040  = 106,971,136
    char* base = (char*)d_ws;
    _Float16* W1h     = (_Float16*)(base);
    _Float16* RSh     = (_Float16*)(base + 11534336);
    float*    bias1   = (float*)(base + 13631488);
    _Float16* outbuf  = (_Float16*)(base + 13647872);
    _Float16* audio0  = (_Float16*)(base + 30425088);
    _Float16* audio1  = (_Float16*)(base + 47726592);
    _Float16* spect_t = (_Float16*)(base + 65028096);

    pack_kernel<<<26640, 256, 0, stream>>>(cond_w, in_w, rs_w, in_b, cond_b,
                                           W1h, RSh, bias1);
    spect_tr_kernel<<<dim3(T_LEN / 64, 1, NB), 256, 0, stream>>>(spect, spect_t);
    guard_zero_kernel<<<512, 256, 0, stream>>>(audio0, audio1);
    start_kernel<<<(NB * T_LEN * 64) / 256, 256, 0, stream>>>(
        audio_in, start_w, start_b, audio0, outbuf);

    for (int i = 0; i < NL; ++i) {
        const _Float16* ard = (i & 1) ? audio1 : audio0;
        _Float16*       awr = (i & 1) ? audio0 : audio1;
        wavenet_layer<<<512, 512, 0, stream>>>(
            ard, awr, spect_t,
            W1h + (size_t)i * 512 * KTOT,
            bias1 + i * 512,
            RSh + (size_t)i * 512 * NC,
            rs_b + i * 512,
            outbuf, 1 << i, (i == NL - 1) ? 1 : 0);
    }

    end_kernel<<<(NB * T_LEN) / 256, 256, 0, stream>>>(outbuf, end_w, end_b, out);
}

// Round 6
// 893.477 us; speedup vs baseline: 1.3478x; 1.3478x over previous
//
#include <hip/hip_runtime.h>
#include <cstdint>
#include <cstddef>

// WaveNet forward, fp16-MFMA v4: fragment-packed weights (coalesced A-loads),
// LDS-transposed coalesced epilogue. Structure otherwise = v3 (verified):
//   t-major activations, 32x32x16 MFMA, NCOL=64, 512-thr WGs, grid 512.
// W1p layout: [kb(88)][rb(16)][lane(64)][j(8)] fp16 -> wave A-load = base+lane*16.
//   row = rb*32 + (lane&31), k = kb*16 + (lane>>5)*8 + j.
// RSp layout: same with kb(16), rb(16).

constexpr int T_LEN = 8192;
constexpr int NB    = 4;
constexpr int NC    = 256;
constexpr int NMEL  = 640;
constexpr int NL    = 8;
constexpr int KTOT  = NMEL + 3 * NC;      // 1408 = 22 * 64
constexpr int GUARD = 128;
constexpr int TROWS = T_LEN + 2 * GUARD;  // 8448
constexpr int NCOL  = 64;

typedef _Float16 half8 __attribute__((ext_vector_type(8)));
typedef _Float16 half4 __attribute__((ext_vector_type(4)));
typedef float f32x16 __attribute__((ext_vector_type(16)));

__device__ __forceinline__ half8 ldg8(const _Float16* p, unsigned boff) {
    return *(const half8*)((const unsigned char*)p + boff);
}

__device__ __forceinline__ void gld_lds16(const void* g, void* l) {
    __builtin_amdgcn_global_load_lds(
        (const __attribute__((address_space(1))) unsigned int*)g,
        (__attribute__((address_space(3))) unsigned int*)l, 16, 0, 0);
}

#define MFMA32(A, B, C) __builtin_amdgcn_mfma_f32_32x32x16_f16((A), (B), (C), 0, 0, 0)

// ------------------------------------------------------------- layer kernel
__global__ __launch_bounds__(512, 4) void wavenet_layer(
    const _Float16* __restrict__ aud_rd_g,   // (B,TROWS,256) ping
    _Float16* __restrict__ aud_wr_g,         // pong
    const _Float16* __restrict__ spect_t,    // (B,T,640)
    const _Float16* __restrict__ W1p,        // packed (88,16,64,8)
    const float* __restrict__ bias1_l,       // (512)
    const _Float16* __restrict__ RSp,        // packed (16,16,64,8)
    const float* __restrict__ rs_b_l,        // (512)
    _Float16* __restrict__ outbuf,           // (B,T,256)
    int dil, int last)
{
    // Bs: buf*16384 + col*128 + pslot*16 ; acts/epilogue union: col*512 + pslot*16
    __shared__ __align__(16) unsigned char smem[32768];

    const int tid = threadIdx.x;
    const int l63 = tid & 63;
    const int c31 = tid & 31;
    const int h2  = (tid >> 5) & 1;
    const int w   = tid >> 6;

    const int bid = blockIdx.x;
    const int swz = (bid & 7) * 64 + (bid >> 3);
    const int n0  = (swz & 127) * NCOL;
    const int b   = swz >> 7;

    const _Float16* aud_rd = aud_rd_g + (size_t)b * TROWS * NC;
    _Float16*       aud_wr = aud_wr_g + (size_t)b * TROWS * NC;
    const _Float16* sp_b   = spect_t + (size_t)b * T_LEN * NMEL;
    _Float16*       out_b  = outbuf + (size_t)b * T_LEN * NC;

    // staging map (unchanged, verified)
    const int sc   = tid >> 3;
    const int ps   = tid & 7;
    const int slog = ps ^ (sc & 7) ^ ((sc >> 3) & 7);
    unsigned voffSb = (unsigned)(((n0 + sc) * NMEL + 8 * slog) * 2);
    unsigned voffAb = (unsigned)(((GUARD + n0 + sc - dil) * NC + 8 * slog) * 2);
    const unsigned dilstep = (unsigned)(dil * 512 - 384);

    // MFMA LDS read constants (unchanged)
    const int xc0 = (c31 & 7) ^ ((c31 >> 3) & 7);
    const int hx0 = ((h2 ^ xc0) << 4);
    const int hx1 = ((h2 ^ xc0 ^ 4) << 4);
    const int rb0 = c31 * 128;
    const int rb1 = (32 + c31) * 128;

    // packed-W byte offsets: lo rows rb=w, hi rows rb=8+w (delta 8192)
    const unsigned voffW = (unsigned)(w * 1024 + l63 * 16);

    const f32x16 fz = {0.f,0.f,0.f,0.f,0.f,0.f,0.f,0.f,0.f,0.f,0.f,0.f,0.f,0.f,0.f,0.f};
    f32x16 acc00 = fz, acc01 = fz, acc10 = fz, acc11 = fz;

#define GLD(SS, BUF)                                                          \
    {                                                                         \
        if ((SS) <= 9) {                                                      \
            gld_lds16((const unsigned char*)sp_b + voffSb,                    \
                      smem + (BUF) * 16384 + tid * 16);                       \
            voffSb += 128;                                                    \
        } else if ((SS) <= 21) {                                              \
            gld_lds16((const unsigned char*)aud_rd + voffAb,                  \
                      smem + (BUF) * 16384 + tid * 16);                       \
            voffAb += ((SS) == 13 || (SS) == 17) ? dilstep : 128u;            \
        }                                                                     \
    }

#define HSTEP(CUR, SS, STEPI)                                                 \
    {                                                                         \
        const unsigned wb_ = voffW + (unsigned)(STEPI) * 65536u;              \
        half8 a0_[4], a1_[4];                                                 \
        _Pragma("unroll") for (int ks = 0; ks < 4; ++ks) {                    \
            a0_[ks] = ldg8(W1p, wb_ + ks * 16384u);                           \
            a1_[ks] = ldg8(W1p, wb_ + ks * 16384u + 8192u);                   \
        }                                                                     \
        GLD(SS, (CUR) ^ 1)                                                    \
        __builtin_amdgcn_s_setprio(1);                                        \
        _Pragma("unroll") for (int ks = 0; ks < 4; ++ks) {                    \
            half8 b0 = *(const half8*)(smem + (CUR) * 16384 + rb0 +           \
                                       ((ks << 5) ^ hx0));                    \
            half8 b1 = *(const half8*)(smem + (CUR) * 16384 + rb1 +           \
                                       ((ks << 5) ^ hx1));                    \
            acc00 = MFMA32(a0_[ks], b0, acc00);                               \
            acc01 = MFMA32(a0_[ks], b1, acc01);                               \
            acc10 = MFMA32(a1_[ks], b0, acc10);                               \
            acc11 = MFMA32(a1_[ks], b1, acc11);                               \
        }                                                                     \
        __builtin_amdgcn_s_setprio(0);                                        \
        __syncthreads();                                                      \
    }

    // prologue: block 0 -> buf0
    GLD(0, 0)
    __syncthreads();

    #pragma unroll 1
    for (int it = 0; it < 11; ++it) {
        HSTEP(0, it * 2 + 1, it * 2)
        HSTEP(1, it * 2 + 2, it * 2 + 1)
    }
#undef HSTEP
#undef GLD

    // ---- gate -> acts in LDS (swizzled; unchanged)
    #pragma unroll
    for (int nn = 0; nn < 2; ++nn) {
        const f32x16& p0v = nn ? acc01 : acc00;
        const f32x16& p1v = nn ? acc11 : acc10;
        const int colb = (32 * nn + c31) * 512;
        const int xcn  = nn ? (xc0 ^ 4) : xc0;
        #pragma unroll
        for (int g = 0; g < 4; ++g) {
            half4 hv;
            #pragma unroll
            for (int r = 0; r < 4; ++r) {
                int ch   = 32 * w + 8 * g + 4 * h2 + r;
                float p0 = p0v[4 * g + r] + bias1_l[ch];
                float p1 = p1v[4 * g + r] + bias1_l[256 + ch];
                float th = 1.f - 2.f / (1.f + __expf(2.f * p0));
                float sg = 1.f / (1.f + __expf(-p1));
                hv[r] = (_Float16)(th * sg);
            }
            int slot = 4 * w + g;
            *(half4*)(smem + colb + ((slot ^ xcn) << 4) + 8 * h2) = hv;
        }
    }
    __syncthreads();

    // ---- rs GEMM: K=256, packed RS (coalesced A)
    f32x16 r00 = fz, r01 = fz, r10 = fz, r11 = fz;
    #pragma unroll
    for (int ksl = 0; ksl < 16; ++ksl) {
        half8 a0 = ldg8(RSp, voffW + (unsigned)ksl * 16384u);
        half8 a1 = ldg8(RSp, voffW + (unsigned)ksl * 16384u + 8192u);
        half8 b0 = *(const half8*)(smem + c31 * 512 + ((ksl << 5) ^ hx0));
        half8 b1 = *(const half8*)(smem + (32 + c31) * 512 + ((ksl << 5) ^ hx1));
        r00 = MFMA32(a0, b0, r00);
        r01 = MFMA32(a0, b1, r01);
        r10 = MFMA32(a1, b0, r10);
        r11 = MFMA32(a1, b1, r11);
    }
    __syncthreads();   // acts reads done; smem reusable

    // ---- epilogue via LDS transpose (coalesced global R/W)
    const int ecol = tid >> 3;                  // t within tile
    const int ecb  = (tid & 7) * 32;            // channel block
    const int excr = (ecol & 7) ^ ((ecol >> 3) & 7);
    const int t_gl = n0 + ecol;

    // pass LO: rsa[:256] -> audio (or outbuf if last)
    #pragma unroll
    for (int nn = 0; nn < 2; ++nn) {
        const f32x16& v0 = nn ? r01 : r00;
        const int colb = (32 * nn + c31) * 512;
        const int xcn  = nn ? (xc0 ^ 4) : xc0;
        #pragma unroll
        for (int g = 0; g < 4; ++g) {
            half4 hv;
            #pragma unroll
            for (int r = 0; r < 4; ++r) {
                int ch = 32 * w + 8 * g + 4 * h2 + r;
                hv[r] = (_Float16)(v0[4 * g + r] + rs_b_l[ch]);
            }
            *(half4*)(smem + colb + ((((4 * w + g)) ^ xcn) << 4) + 8 * h2) = hv;
        }
    }
    __syncthreads();
    if (last) {
        size_t oi = (size_t)t_gl * NC + ecb;
        #pragma unroll
        for (int q = 0; q < 4; ++q) {
            int pslot = (((tid & 7) * 4 + q)) ^ excr;
            half8 v8 = *(const half8*)(smem + ecol * 512 + pslot * 16);
            half8 o  = *(const half8*)(out_b + oi + 8 * q);
            half8 nv;
            #pragma unroll
            for (int r = 0; r < 8; ++r)
                nv[r] = (_Float16)((float)o[r] + (float)v8[r]);
            *(half8*)(out_b + oi + 8 * q) = nv;
        }
    } else {
        size_t ai = (size_t)(GUARD + t_gl) * NC + ecb;
        #pragma unroll
        for (int q = 0; q < 4; ++q) {
            int pslot = (((tid & 7) * 4 + q)) ^ excr;
            half8 v8 = *(const half8*)(smem + ecol * 512 + pslot * 16);
            half8 o  = *(const half8*)(aud_rd + ai + 8 * q);
            half8 nv;
            #pragma unroll
            for (int r = 0; r < 8; ++r)
                nv[r] = (_Float16)((float)o[r] + (float)v8[r]);
            *(half8*)(aud_wr + ai + 8 * q) = nv;
        }
        __syncthreads();
        // pass HI: rsa[256:] -> outbuf accum
        #pragma unroll
        for (int nn = 0; nn < 2; ++nn) {
            const f32x16& v1 = nn ? r11 : r10;
            const int colb = (32 * nn + c31) * 512;
            const int xcn  = nn ? (xc0 ^ 4) : xc0;
            #pragma unroll
            for (int g = 0; g < 4; ++g) {
                half4 hv;
                #pragma unroll
                for (int r = 0; r < 4; ++r) {
                    int ch = 32 * w + 8 * g + 4 * h2 + r;
                    hv[r] = (_Float16)(v1[4 * g + r] + rs_b_l[256 + ch]);
                }
                *(half4*)(smem + colb + ((((4 * w + g)) ^ xcn) << 4) + 8 * h2) = hv;
            }
        }
        __syncthreads();
        size_t oi = (size_t)t_gl * NC + ecb;
        #pragma unroll
        for (int q = 0; q < 4; ++q) {
            int pslot = (((tid & 7) * 4 + q)) ^ excr;
            half8 v8 = *(const half8*)(smem + ecol * 512 + pslot * 16);
            half8 o  = *(const half8*)(out_b + oi + 8 * q);
            half8 nv;
            #pragma unroll
            for (int r = 0; r < 8; ++r)
                nv[r] = (_Float16)((float)o[r] + (float)v8[r]);
            *(half8*)(out_b + oi + 8 * q) = nv;
        }
    }
}

// ------------------------------------------------------------- pack weights
__global__ __launch_bounds__(256) void pack_kernel(
    const float* __restrict__ cond_w, const float* __restrict__ in_w,
    const float* __restrict__ rs_w, const float* __restrict__ in_b,
    const float* __restrict__ cond_b,
    _Float16* __restrict__ W1p, _Float16* __restrict__ RSp,
    float* __restrict__ bias1)
{
    constexpr int SZ_W1 = NL * 512 * KTOT;       // 5,767,168 (=NL*720896)
    constexpr int SZ_RS = NL * 512 * NC;         // 1,048,576 (=NL*131072)
    int idx = blockIdx.x * 256 + threadIdx.x;
    if (idx < SZ_W1) {
        int lyr = idx / 720896;
        int rem = idx - lyr * 720896;
        int kb   = rem >> 13;
        int r2   = rem & 8191;
        int rbb  = r2 >> 9;
        int r3   = r2 & 511;
        int lane = r3 >> 3;
        int j    = r3 & 7;
        int row  = rbb * 32 + (lane & 31);
        int k    = kb * 16 + (lane >> 5) * 8 + j;
        float v;
        if (k < NMEL) {
            v = cond_w[(size_t)(lyr * 512 + row) * NMEL + k];
        } else {
            int kin = k - NMEL;
            int kk = kin >> 8, cc = kin & 255;   // tap-major
            v = in_w[((size_t)(lyr * 512 + row) * NC + cc) * 3 + kk];
        }
        W1p[idx] = (_Float16)v;
    } else if (idx < SZ_W1 + SZ_RS) {
        int i2 = idx - SZ_W1;
        int lyr = i2 >> 17;                      // /131072
        int rem = i2 & 131071;
        int kb   = rem >> 13;
        int r2   = rem & 8191;
        int rbb  = r2 >> 9;
        int r3   = r2 & 511;
        int lane = r3 >> 3;
        int j    = r3 & 7;
        int row  = rbb * 32 + (lane & 31);
        int k    = kb * 16 + (lane >> 5) * 8 + j;
        RSp[i2] = (_Float16)rs_w[(size_t)(lyr * 512 + row) * NC + k];
    } else if (idx < SZ_W1 + SZ_RS + NL * 512) {
        int i3 = idx - SZ_W1 - SZ_RS;
        bias1[i3] = in_b[i3] + cond_b[i3];
    }
}

// ------------------------------------------------- spect fp32 (c,t) -> fp16 (t,c)
__global__ __launch_bounds__(256) void spect_tr_kernel(
    const float* __restrict__ spect, _Float16* __restrict__ spect_t)
{
    int t0 = blockIdx.x * 64;
    int b  = blockIdx.z;
    int tt = threadIdx.x & 63;
    int gg = threadIdx.x >> 6;
    const float* sb = spect + (size_t)b * NMEL * T_LEN + t0 + tt;
    _Float16*    ob = spect_t + (size_t)b * T_LEN * NMEL + (size_t)(t0 + tt) * NMEL;
    #pragma unroll 1
    for (int g = gg; g < 80; g += 4) {
        half8 v;
        #pragma unroll
        for (int j = 0; j < 8; ++j)
            v[j] = (_Float16)sb[(size_t)(8 * g + j) * T_LEN];
        *(half8*)(ob + 8 * g) = v;
    }
}

// ------------------------------------------------------------- guard zero
__global__ __launch_bounds__(256) void guard_zero_kernel(
    _Float16* __restrict__ a0, _Float16* __restrict__ a1)
{
    int idx = blockIdx.x * 256 + threadIdx.x;
    int q  = idx & 16383;
    int rg = q >> 6;
    int ck = q & 63;
    int b  = (idx >> 14) & 3;
    _Float16* base = (idx >> 16) ? a1 : a0;
    int row = (rg < 128) ? rg : rg + 8192;
    half4 z = {};
    *(half4*)(base + (size_t)b * TROWS * NC + (size_t)row * NC + ck * 4) = z;
}

// ------------------------------------------------------------- start conv
__global__ __launch_bounds__(256) void start_kernel(
    const float* __restrict__ audio_in,  // (B,4,T)
    const float* __restrict__ start_w,   // (256,4)
    const float* __restrict__ start_b,   // (256)
    _Float16* __restrict__ audio0,       // (B,TROWS,256)
    _Float16* __restrict__ outbuf)       // (B,T,256) -> zero
{
    int idx = blockIdx.x * 256 + threadIdx.x;
    int c4 = (idx & 63) * 4;
    int t  = (idx >> 6) & (T_LEN - 1);
    int b  = idx >> 19;
    float a[4];
    #pragma unroll
    for (int i = 0; i < 4; ++i)
        a[i] = audio_in[((size_t)b * 4 + i) * T_LEN + t];
    half4 hv;
    #pragma unroll
    for (int r = 0; r < 4; ++r) {
        float acc = start_b[c4 + r];
        #pragma unroll
        for (int i = 0; i < 4; ++i)
            acc += start_w[(c4 + r) * 4 + i] * a[i];
        hv[r] = (_Float16)acc;
    }
    *(half4*)(audio0 + (size_t)b * TROWS * NC + (size_t)(GUARD + t) * NC + c4) = hv;
    half4 z = {};
    *(half4*)(outbuf + (size_t)b * T_LEN * NC + (size_t)t * NC + c4) = z;
}

// ------------------------------------------------------------- end conv
__global__ __launch_bounds__(256) void end_kernel(
    const _Float16* __restrict__ outbuf, // (B,T,256)
    const float* __restrict__ end_w,     // (8,256)
    const float* __restrict__ end_b,     // (8)
    float* __restrict__ out)             // (B,8,T)
{
    int idx = blockIdx.x * 256 + threadIdx.x;
    int t = idx & (T_LEN - 1);
    int b = idx >> 13;
    const _Float16* ob = outbuf + (size_t)b * T_LEN * NC + (size_t)t * NC;
    float acc[8];
    #pragma unroll
    for (int o = 0; o < 8; ++o) acc[o] = end_b[o];
    #pragma unroll 1
    for (int c8 = 0; c8 < 32; ++c8) {
        half8 x = *(const half8*)(ob + c8 * 8);
        #pragma unroll
        for (int j = 0; j < 8; ++j) {
            float xf = (float)x[j];
            #pragma unroll
            for (int o = 0; o < 8; ++o)
                acc[o] += end_w[o * NC + c8 * 8 + j] * xf;
        }
    }
    #pragma unroll
    for (int o = 0; o < 8; ++o)
        out[((size_t)b * 8 + o) * T_LEN + t] = acc[o];
}

// ------------------------------------------------------------- launcher
extern "C" void kernel_launch(void* const* d_in, const int* in_sizes, int n_in,
                              void* d_out, int out_size, void* d_ws, size_t ws_size,
                              hipStream_t stream)
{
    const float* spect    = (const float*)d_in[0];
    const float* audio_in = (const float*)d_in[1];
    const float* start_w  = (const float*)d_in[2];
    const float* start_b  = (const float*)d_in[3];
    const float* cond_w   = (const float*)d_in[4];
    const float* cond_b   = (const float*)d_in[5];
    const float* in_w     = (const float*)d_in[6];
    const float* in_b     = (const float*)d_in[7];
    const float* rs_w     = (const float*)d_in[8];
    const float* rs_b     = (const float*)d_in[9];
    const float* end_w    = (const float*)d_in[10];
    const float* end_b    = (const float*)d_in[11];
    float* out = (float*)d_out;

    char* base = (char*)d_ws;
    _Float16* W1p     = (_Float16*)(base);
    _Float16* RSp     = (_Float16*)(base + 11534336);
    float*    bias1   = (float*)(base + 13631488);
    _Float16* outbuf  = (_Float16*)(base + 13647872);
    _Float16* audio0  = (_Float16*)(base + 30425088);
    _Float16* audio1  = (_Float16*)(base + 47726592);
    _Float16* spect_t = (_Float16*)(base + 65028096);

    pack_kernel<<<26640, 256, 0, stream>>>(cond_w, in_w, rs_w, in_b, cond_b,
                                           W1p, RSp, bias1);
    spect_tr_kernel<<<dim3(T_LEN / 64, 1, NB), 256, 0, stream>>>(spect, spect_t);
    guard_zero_kernel<<<512, 256, 0, stream>>>(audio0, audio1);
    start_kernel<<<(NB * T_LEN * 64) / 256, 256, 0, stream>>>(
        audio_in, start_w, start_b, audio0, outbuf);

    for (int i = 0; i < NL; ++i) {
        const _Float16* ard = (i & 1) ? audio1 : audio0;
        _Float16*       awr = (i & 1) ? audio0 : audio1;
        wavenet_layer<<<512, 512, 0, stream>>>(
            ard, awr, spect_t,
            W1p + (size_t)i * 512 * KTOT,
            bias1 + i * 512,
            RSp + (size_t)i * 512 * NC,
            rs_b + i * 512,
            outbuf, 1 << i, (i == NL - 1) ? 1 : 0);
    }

    end_kernel<<<(NB * T_LEN) / 256, 256, 0, stream>>>(outbuf, end_w, end_b, out);
}